// Round 2
// baseline (192.701 us; speedup 1.0000x reference)
//
#include <hip/hip_runtime.h>
#include <hip/hip_bf16.h>

// Sliding-window attention block: x@Wqkv^T -> flash-attn(window=256, causal) -> @Wproj^T
// T=4096, D=1024, H=16, Hd=64. All MFMA in bf16 (threshold 6.25e-2 permits bf16 path).

#define T_SEQ   4096
#define DM      1024
#define NH      16
#define HD      64
#define WIN     256

typedef unsigned short u16_t;
typedef u16_t  u16v8 __attribute__((ext_vector_type(8)));
typedef __bf16 bf16v8 __attribute__((ext_vector_type(8)));
typedef float  f32v4 __attribute__((ext_vector_type(4)));

__device__ __forceinline__ f32v4 mfma_bf16(u16v8 a, u16v8 b, f32v4 c) {
    return __builtin_amdgcn_mfma_f32_16x16x32_bf16(
        __builtin_bit_cast(bf16v8, a), __builtin_bit_cast(bf16v8, b), c, 0, 0, 0);
}

__device__ __forceinline__ u16_t f2bf(float f) {
    unsigned u = __builtin_bit_cast(unsigned, f);
    u += 0x7fffu + ((u >> 16) & 1u);            // RNE
    return (u16_t)(u >> 16);
}

__device__ __forceinline__ void gload_lds16(const u16_t* g, u16_t* l) {
    __builtin_amdgcn_global_load_lds(
        (const __attribute__((address_space(1))) unsigned int*)g,
        (__attribute__((address_space(3))) unsigned int*)l, 16, 0, 0);
}

// ---------------- fp32 -> bf16 convert (8 elems/thread) ----------------
__global__ void cvt_kernel(const float* __restrict__ in, u16_t* __restrict__ out, int n8) {
    int i = blockIdx.x * blockDim.x + threadIdx.x;
    if (i >= n8) return;
    const float4* p = (const float4*)(in + (size_t)i * 8);
    float4 a = p[0], b = p[1];
    u16v8 o;
    o[0] = f2bf(a.x); o[1] = f2bf(a.y); o[2] = f2bf(a.z); o[3] = f2bf(a.w);
    o[4] = f2bf(b.x); o[5] = f2bf(b.y); o[6] = f2bf(b.z); o[7] = f2bf(b.w);
    *(u16v8*)(out + (size_t)i * 8) = o;
}

// ---------------- bf16 GEMM, C[M,N] = A[M,K] * B[N,K]^T ----------------
// 128x128 tile, BK=32, 4 waves (2x2 of 64x64), global_load_lds w=16.
// LDS swizzle: granule g at row r holds k-chunk (g ^ ((r>>1)&3)) — both-sides
// swizzle via pre-swizzled global source (linear LDS dest, rule #21).
template <typename OutT>
__global__ __launch_bounds__(256) void gemm_bt(const u16_t* __restrict__ A,
                                               const u16_t* __restrict__ B,
                                               OutT* __restrict__ C,
                                               int M, int N, int K) {
    __shared__ u16_t lA[128 * 32];
    __shared__ u16_t lB[128 * 32];
    const int tid = threadIdx.x;
    const int l  = tid & 63;
    const int w  = tid >> 6;
    const int lr = l & 15, ko = l >> 4;
    const int wr = (w >> 1) * 64, wc = (w & 1) * 64;
    const int arow0 = blockIdx.y * 128, bcol0 = blockIdx.x * 128;

    f32v4 acc[4][4];
#pragma unroll
    for (int m = 0; m < 4; ++m)
#pragma unroll
        for (int n = 0; n < 4; ++n) acc[m][n] = f32v4{0.f, 0.f, 0.f, 0.f};

    const int s0 = tid, s1 = tid + 256;
    const int r0 = s0 >> 2, g0 = s0 & 3;
    const int r1 = s1 >> 2, g1 = s1 & 3;
    const int k0q = (g0 ^ ((r0 >> 1) & 3)) * 8;   // inverse-swizzled source k-offset
    const int k1q = (g1 ^ ((r1 >> 1) & 3)) * 8;

    for (int kt = 0; kt < K; kt += 32) {
        __syncthreads();   // previous iter's reads done before overwrite
        gload_lds16(A + (size_t)(arow0 + r0) * K + kt + k0q, lA + s0 * 8);
        gload_lds16(A + (size_t)(arow0 + r1) * K + kt + k1q, lA + s1 * 8);
        gload_lds16(B + (size_t)(bcol0 + r0) * K + kt + k0q, lB + s0 * 8);
        gload_lds16(B + (size_t)(bcol0 + r1) * K + kt + k1q, lB + s1 * 8);
        __syncthreads();   // drains vmcnt before barrier -> staged data visible

        u16v8 af[4], bfv[4];
#pragma unroll
        for (int m = 0; m < 4; ++m) {
            int row = wr + m * 16 + lr;
            af[m] = *(const u16v8*)(lA + row * 32 + (ko ^ ((row >> 1) & 3)) * 8);
        }
#pragma unroll
        for (int n = 0; n < 4; ++n) {
            int row = wc + n * 16 + lr;
            bfv[n] = *(const u16v8*)(lB + row * 32 + (ko ^ ((row >> 1) & 3)) * 8);
        }
#pragma unroll
        for (int m = 0; m < 4; ++m)
#pragma unroll
            for (int n = 0; n < 4; ++n)
                acc[m][n] = mfma_bf16(af[m], bfv[n], acc[m][n]);
    }

    // epilogue: C/D layout col=lane&15, row=(lane>>4)*4+j (m89-verified)
#pragma unroll
    for (int m = 0; m < 4; ++m) {
        int crow0 = arow0 + wr + m * 16 + ko * 4;
#pragma unroll
        for (int n = 0; n < 4; ++n) {
            int ccol = bcol0 + wc + n * 16 + lr;
#pragma unroll
            for (int j = 0; j < 4; ++j) {
                float v = acc[m][n][j];
                if constexpr (sizeof(OutT) == 2)
                    C[(size_t)(crow0 + j) * N + ccol] = (OutT)f2bf(v);
                else
                    C[(size_t)(crow0 + j) * N + ccol] = (OutT)v;
            }
        }
    }
}

// ---------------- V transpose: qkv[t][2048+h*64+d] -> vt[h][d][t] ----------------
__global__ __launch_bounds__(256) void vtrans_kernel(const u16_t* __restrict__ qkv,
                                                     u16_t* __restrict__ vt) {
    __shared__ u16_t tile[64][72];   // +8 pad
    const int t0 = blockIdx.x * 64, h = blockIdx.y;
    const int tid = threadIdx.x;
    {
        int r = tid >> 2, c = (tid & 3) * 16;
        const u16_t* src = qkv + (size_t)(t0 + r) * (3 * DM) + 2 * DM + h * HD + c;
        *(u16v8*)&tile[r][c]     = *(const u16v8*)src;
        *(u16v8*)&tile[r][c + 8] = *(const u16v8*)(src + 8);
    }
    __syncthreads();
    {
        int d = tid >> 2, ts = (tid & 3) * 16;
        u16_t* dst = vt + ((size_t)h * HD + d) * T_SEQ + t0 + ts;
        u16v8 o0, o1;
#pragma unroll
        for (int i = 0; i < 8; ++i) { o0[i] = tile[ts + i][d]; o1[i] = tile[ts + 8 + i][d]; }
        *(u16v8*)dst       = o0;
        *(u16v8*)(dst + 8) = o1;
    }
}

// ---------------- flash attention, sliding window ----------------
// 1 wave = 16 q rows; 32-key chunks; per-wave P relayout via private LDS.
__global__ __launch_bounds__(256) void attn_kernel(const u16_t* __restrict__ qkv,
                                                   const u16_t* __restrict__ vt,
                                                   u16_t* __restrict__ out) {
    __shared__ u16_t pbuf[4][16 * 32];
    const int h = blockIdx.y;
    const int w = threadIdx.x >> 6, l = threadIdx.x & 63;
    const int i0 = blockIdx.x * 64 + w * 16;
    const int lr = l & 15, g = l >> 4;
    u16_t* P = pbuf[w];

    const u16_t* qb = qkv + h * HD;
    const u16_t* kb = qkv + DM + h * HD;

    u16v8 qf0, qf1;
    {
        const u16_t* qrow = qb + (size_t)(i0 + lr) * (3 * DM) + g * 8;
        qf0 = *(const u16v8*)qrow;
        qf1 = *(const u16v8*)(qrow + 32);
    }
    f32v4 o[4];
#pragma unroll
    for (int n = 0; n < 4; ++n) o[n] = f32v4{0.f, 0.f, 0.f, 0.f};
    float m_run[4], l_run[4];
#pragma unroll
    for (int j = 0; j < 4; ++j) { m_run[j] = -1e30f; l_run[j] = 0.f; }

    const int clo = (i0 - (WIN - 1) > 0 ? i0 - (WIN - 1) : 0) & ~31;
    const int chi = (i0 + 15) & ~31;
    for (int c = clo; c <= chi; c += 32) {
        // QK^T: S[16 q][32 k]
        f32v4 s[2];
#pragma unroll
        for (int kt = 0; kt < 2; ++kt) {
            const u16_t* krow = kb + (size_t)(c + kt * 16 + lr) * (3 * DM) + g * 8;
            u16v8 kf0 = *(const u16v8*)krow;
            u16v8 kf1 = *(const u16v8*)(krow + 32);
            f32v4 z = f32v4{0.f, 0.f, 0.f, 0.f};
            z = mfma_bf16(qf0, kf0, z);
            z = mfma_bf16(qf1, kf1, z);
            s[kt] = z;
        }
        float mloc[4], corr[4], rsum[4];
#pragma unroll
        for (int j = 0; j < 4; ++j) {
            const int i = i0 + g * 4 + j;
#pragma unroll
            for (int kt = 0; kt < 2; ++kt) {
                const int jg = c + kt * 16 + lr;
                float v = s[kt][j] * 0.125f;   // Hd^-0.5
                const bool okm = (jg <= i) && (jg >= i - (WIN - 1));
                s[kt][j] = okm ? v : -3e38f;
            }
            mloc[j] = fmaxf(s[0][j], s[1][j]);
        }
#pragma unroll
        for (int d = 1; d < 16; d <<= 1)
#pragma unroll
            for (int j = 0; j < 4; ++j) mloc[j] = fmaxf(mloc[j], __shfl_xor(mloc[j], d, 64));
#pragma unroll
        for (int j = 0; j < 4; ++j) {
            float mnew = fmaxf(m_run[j], mloc[j]);
            corr[j] = __expf(m_run[j] - mnew);
            m_run[j] = mnew;
            float p0 = __expf(s[0][j] - mnew);
            float p1 = __expf(s[1][j] - mnew);
            P[(g * 4 + j) * 32 + lr]      = f2bf(p0);   // C-layout -> row-major P
            P[(g * 4 + j) * 32 + 16 + lr] = f2bf(p1);
            rsum[j] = p0 + p1;
        }
#pragma unroll
        for (int d = 1; d < 16; d <<= 1)
#pragma unroll
            for (int j = 0; j < 4; ++j) rsum[j] += __shfl_xor(rsum[j], d, 64);
#pragma unroll
        for (int j = 0; j < 4; ++j) l_run[j] = l_run[j] * corr[j] + rsum[j];
#pragma unroll
        for (int n = 0; n < 4; ++n)
#pragma unroll
            for (int j = 0; j < 4; ++j) o[n][j] *= corr[j];

        // PV: A-frag from wave-private LDS (compiler orders write->read via lgkmcnt)
        u16v8 pa = *(const u16v8*)(P + lr * 32 + g * 8);
#pragma unroll
        for (int n = 0; n < 4; ++n) {
            const u16_t* vrow = vt + ((size_t)h * HD + n * 16 + lr) * T_SEQ + c + g * 8;
            u16v8 vf = *(const u16v8*)vrow;
            o[n] = mfma_bf16(pa, vf, o[n]);
        }
    }
#pragma unroll
    for (int n = 0; n < 4; ++n)
#pragma unroll
        for (int j = 0; j < 4; ++j) {
            int t = i0 + g * 4 + j;
            out[(size_t)t * DM + h * HD + n * 16 + lr] = f2bf(o[n][j] / l_run[j]);
        }
}

extern "C" void kernel_launch(void* const* d_in, const int* in_sizes, int n_in,
                              void* d_out, int out_size, void* d_ws, size_t ws_size,
                              hipStream_t stream) {
    const float* x     = (const float*)d_in[0];
    const float* wqkv  = (const float*)d_in[1];
    const float* wproj = (const float*)d_in[2];
    float* out = (float*)d_out;
    char* ws = (char*)d_ws;

    // workspace layout (48 MB total):
    u16_t* xb     = (u16_t*)(ws);                        // 8 MB  [0,8M)   (reused as attnb)
    u16_t* wqkvb  = (u16_t*)(ws + (size_t)(8u << 20));   // 6 MB  [8M,14M)
    u16_t* wprojb = (u16_t*)(ws + (size_t)(14u << 20));  // 2 MB  [14M,16M)
    u16_t* qkvb   = (u16_t*)(ws + (size_t)(16u << 20));  // 24 MB [16M,40M)
    u16_t* vt     = (u16_t*)(ws + (size_t)(40u << 20));  // 8 MB  [40M,48M)
    u16_t* attnb  = (u16_t*)(ws);                        // overlays xb (x dead after QKV GEMM)

    const int n8x = T_SEQ * DM / 8, n8q = 3 * DM * DM / 8, n8p = DM * DM / 8;
    cvt_kernel<<<(n8x + 255) / 256, 256, 0, stream>>>(x, xb, n8x);
    cvt_kernel<<<(n8q + 255) / 256, 256, 0, stream>>>(wqkv, wqkvb, n8q);
    cvt_kernel<<<(n8p + 255) / 256, 256, 0, stream>>>(wproj, wprojb, n8p);

    gemm_bt<u16_t><<<dim3(3 * DM / 128, T_SEQ / 128), 256, 0, stream>>>(
        xb, wqkvb, qkvb, T_SEQ, 3 * DM, DM);

    vtrans_kernel<<<dim3(T_SEQ / 64, NH), 256, 0, stream>>>(qkvb, vt);

    attn_kernel<<<dim3(T_SEQ / 64, NH), 256, 0, stream>>>(qkvb, vt, attnb);

    gemm_bt<float><<<dim3(DM / 128, T_SEQ / 128), 256, 0, stream>>>(
        attnb, wprojb, out, T_SEQ, DM, DM);
}

// Round 4
// 174.966 us; speedup vs baseline: 1.1014x; 1.1014x over previous
//
#include <hip/hip_runtime.h>
#include <hip/hip_bf16.h>

// Sliding-window attention block: x@Wqkv^T -> flash-attn(window=256, causal) -> @Wproj^T
// T=4096, D=1024, H=16, Hd=64. All MFMA in bf16.

#define T_SEQ   4096
#define DM      1024
#define NH      16
#define HD      64
#define WIN     256

typedef unsigned short u16_t;
typedef u16_t  u16v8 __attribute__((ext_vector_type(8)));
typedef __bf16 bf16v8 __attribute__((ext_vector_type(8)));
typedef float  f32v4 __attribute__((ext_vector_type(4)));

__device__ __forceinline__ f32v4 mfma_bf16(u16v8 a, u16v8 b, f32v4 c) {
    return __builtin_amdgcn_mfma_f32_16x16x32_bf16(
        __builtin_bit_cast(bf16v8, a), __builtin_bit_cast(bf16v8, b), c, 0, 0, 0);
}

__device__ __forceinline__ u16_t f2bf(float f) {
    unsigned u = __builtin_bit_cast(unsigned, f);
    u += 0x7fffu + ((u >> 16) & 1u);            // RNE
    return (u16_t)(u >> 16);
}

__device__ __forceinline__ float exp2_fast(float x) {
    return __builtin_amdgcn_exp2f(x);            // v_exp_f32 (base-2)
}

__device__ __forceinline__ void gload_lds16(const u16_t* g, u16_t* l) {
    __builtin_amdgcn_global_load_lds(
        (const __attribute__((address_space(1))) unsigned int*)g,
        (__attribute__((address_space(3))) unsigned int*)l, 16, 0, 0);
}

// ---------------- fp32 -> bf16 convert (8 elems/thread) ----------------
__global__ void cvt_kernel(const float* __restrict__ in, u16_t* __restrict__ out, int n8) {
    int i = blockIdx.x * blockDim.x + threadIdx.x;
    if (i >= n8) return;
    const float4* p = (const float4*)(in + (size_t)i * 8);
    float4 a = p[0], b = p[1];
    u16v8 o;
    o[0] = f2bf(a.x); o[1] = f2bf(a.y); o[2] = f2bf(a.z); o[3] = f2bf(a.w);
    o[4] = f2bf(b.x); o[5] = f2bf(b.y); o[6] = f2bf(b.z); o[7] = f2bf(b.w);
    *(u16v8*)(out + (size_t)i * 8) = o;
}

// ---------------- bf16 GEMM, C[M,N] = A[M,K] * B[N,K]^T (unchanged) ----------------
template <typename OutT>
__global__ __launch_bounds__(256) void gemm_bt(const u16_t* __restrict__ A,
                                               const u16_t* __restrict__ B,
                                               OutT* __restrict__ C,
                                               int M, int N, int K) {
    __shared__ u16_t lA[128 * 32];
    __shared__ u16_t lB[128 * 32];
    const int tid = threadIdx.x;
    const int l  = tid & 63;
    const int w  = tid >> 6;
    const int lr = l & 15, ko = l >> 4;
    const int wr = (w >> 1) * 64, wc = (w & 1) * 64;
    const int arow0 = blockIdx.y * 128, bcol0 = blockIdx.x * 128;

    f32v4 acc[4][4];
#pragma unroll
    for (int m = 0; m < 4; ++m)
#pragma unroll
        for (int n = 0; n < 4; ++n) acc[m][n] = f32v4{0.f, 0.f, 0.f, 0.f};

    const int s0 = tid, s1 = tid + 256;
    const int r0 = s0 >> 2, g0 = s0 & 3;
    const int r1 = s1 >> 2, g1 = s1 & 3;
    const int k0q = (g0 ^ ((r0 >> 1) & 3)) * 8;
    const int k1q = (g1 ^ ((r1 >> 1) & 3)) * 8;

    for (int kt = 0; kt < K; kt += 32) {
        __syncthreads();
        gload_lds16(A + (size_t)(arow0 + r0) * K + kt + k0q, lA + s0 * 8);
        gload_lds16(A + (size_t)(arow0 + r1) * K + kt + k1q, lA + s1 * 8);
        gload_lds16(B + (size_t)(bcol0 + r0) * K + kt + k0q, lB + s0 * 8);
        gload_lds16(B + (size_t)(bcol0 + r1) * K + kt + k1q, lB + s1 * 8);
        __syncthreads();

        u16v8 af[4], bfv[4];
#pragma unroll
        for (int m = 0; m < 4; ++m) {
            int row = wr + m * 16 + lr;
            af[m] = *(const u16v8*)(lA + row * 32 + (ko ^ ((row >> 1) & 3)) * 8);
        }
#pragma unroll
        for (int n = 0; n < 4; ++n) {
            int row = wc + n * 16 + lr;
            bfv[n] = *(const u16v8*)(lB + row * 32 + (ko ^ ((row >> 1) & 3)) * 8);
        }
#pragma unroll
        for (int m = 0; m < 4; ++m)
#pragma unroll
            for (int n = 0; n < 4; ++n)
                acc[m][n] = mfma_bf16(af[m], bfv[n], acc[m][n]);
    }

#pragma unroll
    for (int m = 0; m < 4; ++m) {
        int crow0 = arow0 + wr + m * 16 + ko * 4;
#pragma unroll
        for (int n = 0; n < 4; ++n) {
            int ccol = bcol0 + wc + n * 16 + lr;
#pragma unroll
            for (int j = 0; j < 4; ++j) {
                float v = acc[m][n][j];
                if constexpr (sizeof(OutT) == 2)
                    C[(size_t)(crow0 + j) * N + ccol] = (OutT)f2bf(v);
                else
                    C[(size_t)(crow0 + j) * N + ccol] = (OutT)v;
            }
        }
    }
}

// ---------------- V transpose: qkv[t][2048+h*64+d] -> vt[h][d][t] ----------------
__global__ __launch_bounds__(256) void vtrans_kernel(const u16_t* __restrict__ qkv,
                                                     u16_t* __restrict__ vt) {
    __shared__ u16_t tile[64][72];   // +8 pad
    const int t0 = blockIdx.x * 64, h = blockIdx.y;
    const int tid = threadIdx.x;
    {
        int r = tid >> 2, c = (tid & 3) * 16;
        const u16_t* src = qkv + (size_t)(t0 + r) * (3 * DM) + 2 * DM + h * HD + c;
        *(u16v8*)&tile[r][c]     = *(const u16v8*)src;
        *(u16v8*)&tile[r][c + 8] = *(const u16v8*)(src + 8);
    }
    __syncthreads();
    {
        int d = tid >> 2, ts = (tid & 3) * 16;
        u16_t* dst = vt + ((size_t)h * HD + d) * T_SEQ + t0 + ts;
        u16v8 o0, o1;
#pragma unroll
        for (int i = 0; i < 8; ++i) { o0[i] = tile[ts + i][d]; o1[i] = tile[ts + 8 + i][d]; }
        *(u16v8*)dst       = o0;
        *(u16v8*)(dst + 8) = o1;
    }
}

// ---------------- flash attention, sliding window (v2) ----------------
// Block = 4 waves, 64 q rows, one head. K/V staged in block-shared LDS,
// 64-key chunks, double-buffered. All tiles XOR-swizzled: chunk16B' = chunk16B ^ (row&7).
// All 4 waves need the identical chunk set {max(q0-256,0)..q0 step 64} -> no divergence.
__global__ __launch_bounds__(256) void attn_kernel(const u16_t* __restrict__ qkv,
                                                   const u16_t* __restrict__ vt,
                                                   u16_t* __restrict__ out) {
    __shared__ u16_t lK[2][64 * 64];
    __shared__ u16_t lV[2][64 * 64];
    __shared__ u16_t pbuf[4][16 * 64];

    const int h = blockIdx.y;
    const int q0 = blockIdx.x * 64;
    const int tid = threadIdx.x;
    const int w = tid >> 6, l = tid & 63;
    const int lr = l & 15, g = l >> 4;
    const int i0 = q0 + w * 16;
    u16_t* P = pbuf[w];

    // staging indices: thread covers 16B chunk c8l of row r_st (+32 for pass 1)
    const int r_st = tid >> 3;          // 0..31
    const int c8l  = tid & 7;
    const u16_t* kBase = qkv + DM + h * HD;                 // row stride 3*DM
    const u16_t* vBase = vt + (size_t)h * HD * T_SEQ;       // row stride T_SEQ

    // Q fragments (once)
    u16v8 qf0, qf1;
    {
        const u16_t* qrow = qkv + h * HD + (size_t)(i0 + lr) * (3 * DM) + g * 8;
        qf0 = *(const u16v8*)qrow;
        qf1 = *(const u16v8*)(qrow + 32);
    }

    f32v4 o[4];
#pragma unroll
    for (int n = 0; n < 4; ++n) o[n] = f32v4{0.f, 0.f, 0.f, 0.f};
    float m_run[4], l_run[4];
#pragma unroll
    for (int j = 0; j < 4; ++j) { m_run[j] = -1e30f; l_run[j] = 0.f; }

    const int c0 = (q0 >= WIN) ? q0 - WIN : 0;
    const int nch = ((q0 - c0) >> 6) + 1;

#define STAGE_KV(buf, cc)                                                              \
    do {                                                                               \
        _Pragma("unroll")                                                              \
        for (int p = 0; p < 2; ++p) {                                                  \
            int rr = r_st + p * 32;                                                    \
            int cs = c8l ^ (rr & 7);                                                   \
            gload_lds16(kBase + (size_t)(cc + rr) * (3 * DM) + cs * 8,                 \
                        lK[buf] + (size_t)(rr * 64 + c8l * 8));                        \
            gload_lds16(vBase + (size_t)rr * T_SEQ + (cc) + cs * 8,                    \
                        lV[buf] + (size_t)(rr * 64 + c8l * 8));                        \
        }                                                                              \
    } while (0)

    STAGE_KV(0, c0);

    const float sc = 0.125f * 1.4426950408889634f;   // Hd^-0.5 * log2(e)

    for (int ci = 0; ci < nch; ++ci) {
        const int c = c0 + (ci << 6);
        const int cur = ci & 1;
        __syncthreads();                      // staged data for `cur` ready; prev reads done
        if (ci + 1 < nch) STAGE_KV(cur ^ 1, c + 64);

        const u16_t* K = lK[cur];
        const u16_t* V = lV[cur];

        // ---- QK^T: S[16 q][64 k] ----
        f32v4 s[4];
#pragma unroll
        for (int kt = 0; kt < 4; ++kt) {
            int krow = kt * 16 + lr;
            u16v8 k0 = *(const u16v8*)(K + krow * 64 + ((g     ^ (krow & 7)) * 8));
            u16v8 k1 = *(const u16v8*)(K + krow * 64 + (((4+g) ^ (krow & 7)) * 8));
            f32v4 z = f32v4{0.f, 0.f, 0.f, 0.f};
            z = mfma_bf16(qf0, k0, z);
            z = mfma_bf16(qf1, k1, z);
            s[kt] = z;
        }

        // ---- mask + scale (log2 domain) ----
        const bool full = (c + 63 <= i0) && (c >= i0 - 240);   // wave-uniform
        if (full) {
#pragma unroll
            for (int kt = 0; kt < 4; ++kt)
#pragma unroll
                for (int j = 0; j < 4; ++j) s[kt][j] *= sc;
        } else {
#pragma unroll
            for (int j = 0; j < 4; ++j) {
                const int i = i0 + g * 4 + j;
#pragma unroll
                for (int kt = 0; kt < 4; ++kt) {
                    const int jg = c + kt * 16 + lr;
                    float v = s[kt][j] * sc;
                    const bool okm = (jg <= i) && (jg >= i - (WIN - 1));
                    s[kt][j] = okm ? v : -3e38f;
                }
            }
        }

        // ---- online softmax ----
        float mloc[4], corr[4], rsum[4];
#pragma unroll
        for (int j = 0; j < 4; ++j)
            mloc[j] = fmaxf(fmaxf(s[0][j], s[1][j]), fmaxf(s[2][j], s[3][j]));
#pragma unroll
        for (int d = 1; d < 16; d <<= 1)
#pragma unroll
            for (int j = 0; j < 4; ++j) mloc[j] = fmaxf(mloc[j], __shfl_xor(mloc[j], d, 64));
#pragma unroll
        for (int j = 0; j < 4; ++j) {
            float mnew = fmaxf(m_run[j], mloc[j]);
            corr[j] = exp2_fast(m_run[j] - mnew);
            m_run[j] = mnew;
            rsum[j] = 0.f;
        }
#pragma unroll
        for (int kt = 0; kt < 4; ++kt)
#pragma unroll
            for (int j = 0; j < 4; ++j) {
                float p = exp2_fast(s[kt][j] - m_run[j]);
                rsum[j] += p;
                int rP = g * 4 + j;
                int col = kt * 16 + lr;
                int c8 = col >> 3;
                P[rP * 64 + ((c8 ^ (rP & 7)) * 8 + (col & 7))] = f2bf(p);
            }
#pragma unroll
        for (int d = 1; d < 16; d <<= 1)
#pragma unroll
            for (int j = 0; j < 4; ++j) rsum[j] += __shfl_xor(rsum[j], d, 64);
#pragma unroll
        for (int j = 0; j < 4; ++j) l_run[j] = l_run[j] * corr[j] + rsum[j];
#pragma unroll
        for (int n = 0; n < 4; ++n)
#pragma unroll
            for (int j = 0; j < 4; ++j) o[n][j] *= corr[j];

        // ---- PV: O[16 q][64 d] += P[16][64] * V^T tiles ----
        u16v8 pa0 = *(const u16v8*)(P + lr * 64 + ((g     ^ (lr & 7)) * 8));
        u16v8 pa1 = *(const u16v8*)(P + lr * 64 + (((4+g) ^ (lr & 7)) * 8));
#pragma unroll
        for (int n = 0; n < 4; ++n) {
            int vrow = n * 16 + lr;
            u16v8 v0 = *(const u16v8*)(V + vrow * 64 + ((g     ^ (vrow & 7)) * 8));
            u16v8 v1 = *(const u16v8*)(V + vrow * 64 + (((4+g) ^ (vrow & 7)) * 8));
            o[n] = mfma_bf16(pa0, v0, o[n]);
            o[n] = mfma_bf16(pa1, v1, o[n]);
        }
    }
#undef STAGE_KV

#pragma unroll
    for (int n = 0; n < 4; ++n)
#pragma unroll
        for (int j = 0; j < 4; ++j) {
            int t = i0 + g * 4 + j;
            out[(size_t)t * DM + h * HD + n * 16 + lr] = f2bf(o[n][j] / l_run[j]);
        }
}

extern "C" void kernel_launch(void* const* d_in, const int* in_sizes, int n_in,
                              void* d_out, int out_size, void* d_ws, size_t ws_size,
                              hipStream_t stream) {
    const float* x     = (const float*)d_in[0];
    const float* wqkv  = (const float*)d_in[1];
    const float* wproj = (const float*)d_in[2];
    float* out = (float*)d_out;
    char* ws = (char*)d_ws;

    u16_t* xb     = (u16_t*)(ws);                        // 8 MB  [0,8M)
    u16_t* wqkvb  = (u16_t*)(ws + (size_t)(8u << 20));   // 6 MB
    u16_t* wprojb = (u16_t*)(ws + (size_t)(14u << 20));  // 2 MB
    u16_t* qkvb   = (u16_t*)(ws + (size_t)(16u << 20));  // 24 MB
    u16_t* vt     = (u16_t*)(ws + (size_t)(40u << 20));  // 8 MB
    u16_t* attnb  = (u16_t*)(ws);                        // overlays xb (x dead after QKV GEMM)

    const int n8x = T_SEQ * DM / 8, n8q = 3 * DM * DM / 8, n8p = DM * DM / 8;
    cvt_kernel<<<(n8x + 255) / 256, 256, 0, stream>>>(x, xb, n8x);
    cvt_kernel<<<(n8q + 255) / 256, 256, 0, stream>>>(wqkv, wqkvb, n8q);
    cvt_kernel<<<(n8p + 255) / 256, 256, 0, stream>>>(wproj, wprojb, n8p);

    gemm_bt<u16_t><<<dim3(3 * DM / 128, T_SEQ / 128), 256, 0, stream>>>(
        xb, wqkvb, qkvb, T_SEQ, 3 * DM, DM);

    vtrans_kernel<<<dim3(T_SEQ / 64, NH), 256, 0, stream>>>(qkvb, vt);

    attn_kernel<<<dim3(T_SEQ / 64, NH), 256, 0, stream>>>(qkvb, vt, attnb);

    gemm_bt<float><<<dim3(DM / 128, T_SEQ / 128), 256, 0, stream>>>(
        attnb, wprojb, out, T_SEQ, DM, DM);
}